// Round 10
// baseline (2146.066 us; speedup 1.0000x reference)
//
#include <hip/hip_runtime.h>
#include <hip/hip_bf16.h>
#include <stdint.h>

namespace {

constexpr int C = 64, H = 128, W = 128, HK = 640, WK = 640;
constexpr long long CSTR = (long long)HK * WK;   // channel stride in fkv
constexpr int PIX = 8;            // query pixels per tile
constexpr int XD = 40;            // kv columns per tile
constexpr int THREADS = 256;      // 4 waves

__device__ inline unsigned int packbf2(float lo, float hi) {
    __hip_bfloat162 h2 = __float22bfloat162_rn(make_float2(lo, hi));
    return *reinterpret_cast<unsigned int*>(&h2);
}
__device__ inline float blo(unsigned int u) { return __uint_as_float(u << 16); }
__device__ inline float bhi(unsigned int u) { return __uint_as_float(u & 0xFFFF0000u); }

// ---------------- prep: Wqk = 0.125 * Wk^T Wq  (16 KB scratch) ----------------
__global__ void prep_wqk(const float* __restrict__ Wq, const float* __restrict__ Wk,
                         float* __restrict__ Wqk) {
    int tid = blockIdx.x * 256 + threadIdx.x;    // 4096 = 64*64
    int i = tid >> 6, j = tid & 63;
    float acc = 0.f;
    #pragma unroll 8
    for (int c = 0; c < 64; ++c) acc = fmaf(Wk[c * 64 + i], Wq[c * 64 + j], acc);
    Wqk[i * 64 + j] = 0.125f * acc;
}

// ---- R5 staging: tile T -> bf16 swizzled slab + fq_lds ----
__device__ __forceinline__ void stage_tile(int T, const float* __restrict__ fq,
                                           const float* __restrict__ fkv,
                                           uint32_t* slab, float* fq_lds, int t) {
    const int wb = T & 15, h = (T >> 4) & 127, b = T >> 11;
    const int row0 = 5 * h, col0 = XD * wb, w0q = PIX * wb;
    {
        const int p = t & 7, c = t >> 3;         // c in 0..31
        fq_lds[p * 68 + c]      = fq[((size_t)(b * 64 + c) << 14) + h * 128 + w0q + p];
        fq_lds[p * 68 + c + 32] = fq[((size_t)(b * 64 + c + 32) << 14) + h * 128 + w0q + p];
    }
    const float* kvb = fkv + (size_t)b * C * CSTR;
    for (int i = t; i < 800; i += THREADS) {     // 10 x4 * 5 y * 16 c4
        const int x4 = i % 10;
        const int y  = (i / 10) % 5;
        const int c4 = i / 50;
        const int xb = 4 * x4;
        const float* g = kvb + (size_t)(4 * c4) * CSTR + (size_t)(row0 + y) * WK + (col0 + xb);
        float4 F0 = *(const float4*)(g);
        float4 F1 = *(const float4*)(g + CSTR);
        float4 F2 = *(const float4*)(g + 2 * CSTR);
        float4 F3 = *(const float4*)(g + 3 * CSTR);
        const float* f0 = (const float*)&F0; const float* f1 = (const float*)&F1;
        const float* f2 = (const float*)&F2; const float* f3 = (const float*)&F3;
        #pragma unroll
        for (int dx = 0; dx < 4; ++dx) {
            const int x = xb + dx;
            const int base = (y * XD + x) * 32;
            const int sw = (((x & 7) ^ y) << 2);
            slab[base + ((2 * c4)     ^ sw)] = packbf2(f0[dx], f1[dx]);
            slab[base + ((2 * c4 + 1) ^ sw)] = packbf2(f2[dx], f3[dx]);
        }
    }
}

// ---- R5 compute: qk -> logits/softmax -> wsum -> out (3 interior barriers) ----
__device__ __forceinline__ void compute_tile(int T, const float* __restrict__ Wqk,
                                             const float* __restrict__ Wv,
                                             const uint32_t* slab, const float* fq_lds,
                                             float* qk_lds, float* lg, uint32_t* wsum,
                                             float* dst, int t, bool store) {
    const int wb = T & 15, h = (T >> 4) & 127, b = T >> 11;
    const int w0q = PIX * wb;

    {   // qk[l][i] = sum_j Wqk[i][j] * fq_lds[l][j]
        const int l = t & 7, i0 = t >> 3;
        const float4* wr0 = (const float4*)(Wqk + i0 * 64);
        const float4* wr1 = (const float4*)(Wqk + (i0 + 32) * 64);
        const float4* fv  = (const float4*)(fq_lds + l * 68);
        float a0 = 0.f, a1 = 0.f;
        #pragma unroll
        for (int j = 0; j < 16; ++j) {
            float4 f = fv[j], w0 = wr0[j], w1 = wr1[j];
            a0 = fmaf(w0.x, f.x, a0); a0 = fmaf(w0.y, f.y, a0);
            a0 = fmaf(w0.z, f.z, a0); a0 = fmaf(w0.w, f.w, a0);
            a1 = fmaf(w1.x, f.x, a1); a1 = fmaf(w1.y, f.y, a1);
            a1 = fmaf(w1.z, f.z, a1); a1 = fmaf(w1.w, f.w, a1);
        }
        qk_lds[l * 68 + i0]      = a0;
        qk_lds[l * 68 + i0 + 32] = a1;
    }
    __syncthreads();

    {   // logits + in-wave softmax
        const int l = t >> 5;
        const int n = t & 31;
        float v = -1e30f;
        if (n < 25) {
            const int ky = n / 5, kx = n - 5 * (n / 5);
            const int x = 5 * l + kx;
            const int base = (ky * XD + x) * 32;
            const int sw7 = (x & 7) ^ ky;
            const float4* qv = (const float4*)(qk_lds + l * 68);
            float acc = 0.f;
            #pragma unroll
            for (int j = 0; j < 8; ++j) {
                uint4 u = *(const uint4*)&slab[base + 4 * (j ^ sw7)];
                float4 qa = qv[2 * j], qb = qv[2 * j + 1];
                acc = fmaf(qa.x, blo(u.x), acc); acc = fmaf(qa.y, bhi(u.x), acc);
                acc = fmaf(qa.z, blo(u.y), acc); acc = fmaf(qa.w, bhi(u.y), acc);
                acc = fmaf(qb.x, blo(u.z), acc); acc = fmaf(qb.y, bhi(u.z), acc);
                acc = fmaf(qb.z, blo(u.w), acc); acc = fmaf(qb.w, bhi(u.w), acc);
            }
            v = acc;
        }
        float m = v;
        #pragma unroll
        for (int off = 16; off; off >>= 1) m = fmaxf(m, __shfl_xor(m, off, 32));
        float e = __expf(v - m);
        float s = e;
        #pragma unroll
        for (int off = 16; off; off >>= 1) s += __shfl_xor(s, off, 32);
        if (n < 25) lg[l * 26 + n] = e / s;
    }
    __syncthreads();

    {   // wsum[l][slot] = sum_n a[l][n] * slab[n][slot]
        const int l = t >> 5, s = t & 31;
        float alo = 0.f, ahi = 0.f;
        #pragma unroll
        for (int n2 = 0; n2 < 25; ++n2) {
            const int ky = n2 / 5, kx = n2 - 5 * ky;
            const int x = 5 * l + kx;
            const unsigned int u = slab[(ky * XD + x) * 32 + (s ^ ((((x & 7) ^ ky)) << 2))];
            const float a = lg[l * 26 + n2];
            alo = fmaf(a, blo(u), alo);
            ahi = fmaf(a, bhi(u), ahi);
        }
        wsum[l * 36 + s] = packbf2(alo, ahi);
    }
    __syncthreads();

    {   // out = fq + Wv @ wsum  (no per-thread array -> no scratch)
        const int p = t & 7, o0 = t >> 3;
        const uint4* wsr = (const uint4*)(wsum + p * 36);
        const float4* wv0 = (const float4*)(Wv + o0 * 64);
        const float4* wv1 = (const float4*)(Wv + (o0 + 32) * 64);
        float a0 = fq_lds[p * 68 + o0];
        float a1 = fq_lds[p * 68 + o0 + 32];
        #pragma unroll
        for (int g8 = 0; g8 < 8; ++g8) {
            uint4 u = wsr[g8];
            float4 wa0 = wv0[2 * g8], wb0 = wv0[2 * g8 + 1];
            float4 wa1 = wv1[2 * g8], wb1 = wv1[2 * g8 + 1];
            a0 = fmaf(wa0.x, blo(u.x), a0); a0 = fmaf(wa0.y, bhi(u.x), a0);
            a0 = fmaf(wa0.z, blo(u.y), a0); a0 = fmaf(wa0.w, bhi(u.y), a0);
            a0 = fmaf(wb0.x, blo(u.z), a0); a0 = fmaf(wb0.y, bhi(u.z), a0);
            a0 = fmaf(wb0.z, blo(u.w), a0); a0 = fmaf(wb0.w, bhi(u.w), a0);
            a1 = fmaf(wa1.x, blo(u.x), a1); a1 = fmaf(wa1.y, bhi(u.x), a1);
            a1 = fmaf(wa1.z, blo(u.y), a1); a1 = fmaf(wa1.w, bhi(u.y), a1);
            a1 = fmaf(wb1.x, blo(u.z), a1); a1 = fmaf(wb1.y, bhi(u.z), a1);
            a1 = fmaf(wb1.z, blo(u.w), a1); a1 = fmaf(wb1.w, bhi(u.w), a1);
        }
        asm volatile("" :: "v"(a0), "v"(a1));    // keep live when !store (ablation, rule 17)
        if (store) {
            const size_t ob = ((size_t)(b * 64 + o0) << 14) + h * 128 + w0q + p;
            dst[ob] = a0;
            dst[ob + ((size_t)32 << 14)] = a1;
        }
    }
}

// V=0: full x2 real work. V=1: stage-only x8 real. V=2: compute-only x16 real.
template<int V>
__global__ __launch_bounds__(THREADS, 5)
void cag_k(const float* __restrict__ fq, const float* __restrict__ fkv,
           const float* __restrict__ Wqk, const float* __restrict__ Wv,
           float* __restrict__ out, uint32_t* __restrict__ ws1,
           float* __restrict__ ws2) {
    __shared__ uint32_t slab[5 * XD * 32];       // 25600 B
    __shared__ float fq_lds[PIX * 68];
    __shared__ float qk_lds[PIX * 68];
    __shared__ float lg[PIX * 26];
    __shared__ uint32_t wsum[PIX * 36];

    const int t = threadIdx.x, bid = blockIdx.x;

    if constexpr (V == 0) {
        #pragma unroll 1
        for (int k = 0; k < 4; ++k) {            // each real tile exactly twice
            int zz = 0; asm volatile("" : "+v"(zz));
            const int T = ((bid + k * 4096) & 8191) + zz;
            stage_tile(T, fq, fkv, slab, fq_lds, t);
            __syncthreads();
            compute_tile(T, Wqk, Wv, slab, fq_lds, qk_lds, lg, wsum, out, t, true);
            __syncthreads();
        }
    } else if constexpr (V == 1) {
        uint32_t acc = 0;
        #pragma unroll 1
        for (int k = 0; k < 16; ++k) {
            int zz = 0; asm volatile("" : "+v"(zz));
            const int T = ((bid + k * 512) & 8191) + zz;
            stage_tile(T, fq, fkv, slab, fq_lds, t);
            __syncthreads();
            acc += slab[(t * 25 + k) & 4095];    // consume -> staging not DCE'd
            __syncthreads();
        }
        ws1[(bid * 256 + t) & 65535] = acc;
    } else {
        for (int i = t; i < 5 * XD * 32; i += THREADS) slab[i] = (uint32_t)i * 2654435761u;
        for (int i = t; i < PIX * 68; i += THREADS) fq_lds[i] = (float)((i * 97) & 31) * 0.03f;
        __syncthreads();
        #pragma unroll 1
        for (int k = 0; k < 32; ++k) {
            int zz = 0; asm volatile("" : "+v"(zz));
            const int T = (bid & 8191) + zz;
            compute_tile(T, Wqk, Wv, slab, fq_lds, qk_lds, lg, wsum, ws2, t, k == 31);
            __syncthreads();
        }
    }
}

} // namespace

extern "C" void kernel_launch(void* const* d_in, const int* in_sizes, int n_in,
                              void* d_out, int out_size, void* d_ws, size_t ws_size,
                              hipStream_t stream) {
    (void)in_sizes; (void)n_in; (void)ws_size; (void)out_size;
    const float* fq  = (const float*)d_in[0];
    const float* fkv = (const float*)d_in[1];
    const float* Wq  = (const float*)d_in[2];
    const float* Wk  = (const float*)d_in[3];
    const float* Wv  = (const float*)d_in[4];
    float* out = (float*)d_out;
    // ws carve: Wqk @0 (16KB) | V1 sink @64KB (256KB) | V2 sink @1MB (16.8MB)
    float*    Wqk = (float*)d_ws;
    uint32_t* ws1 = (uint32_t*)((char*)d_ws + (64 << 10));
    float*    ws2 = (float*)((char*)d_ws + (1 << 20));

    prep_wqk  <<<dim3(16),   dim3(256),     0, stream>>>(Wq, Wk, Wqk);
    cag_k<0>  <<<dim3(4096), dim3(THREADS), 0, stream>>>(fq, fkv, Wqk, Wv, out, ws1, ws2);
    cag_k<1>  <<<dim3(4096), dim3(THREADS), 0, stream>>>(fq, fkv, Wqk, Wv, out, ws1, ws2);
    cag_k<2>  <<<dim3(4096), dim3(THREADS), 0, stream>>>(fq, fkv, Wqk, Wv, out, ws1, ws2);
}